// Round 3
// baseline (454.443 us; speedup 1.0000x reference)
//
#include <hip/hip_runtime.h>

// Problem constants
#define B_  4096
#define D_  1024
#define R_  2048
#define MAXD 2560

typedef _Float16 half8 __attribute__((ext_vector_type(8)));  // 8 fp16 = 4 VGPRs (MFMA frag)
typedef _Float16 half4 __attribute__((ext_vector_type(4)));  // 8-byte LDS store
typedef float    f32x4 __attribute__((ext_vector_type(4)));
typedef float    f32x2 __attribute__((ext_vector_type(2)));

constexpr int BM = 128;      // M tile (batch rows)
constexpr int BN = 64;       // N tile (reservoir cols)
constexpr int BK = 32;       // K chunk (elems)
constexpr int NCHUNK = (D_ + R_) / BK;   // 96
constexpr int NCH1   = D_ / BK;          // 32 (gate + Win phase)

// ---- packed hi/lo plane layout in workspace (units = 16B slots = 4 elems) ----
// Each slot: halves {h0,h1,h2,h3, l0,l1,l2,l3} -- same byte geometry as the
// fp32 source (4 B/elem), so staging address math is unchanged vs fp32.
constexpr size_t XP_OFF   = 0;                                  // B x D
constexpr size_t PP_OFF   = XP_OFF   + (size_t)B_ * D_ / 4;     // B x R (first R cols of P)
constexpr size_t WINP_OFF = PP_OFF   + (size_t)B_ * R_ / 4;     // R x D
constexpr size_t WRESP_OFF= WINP_OFF + (size_t)R_ * D_ / 4;     // R x R
constexpr size_t WGP_OFF  = WRESP_OFF+ (size_t)R_ * R_ / 4;     // 3R x D
constexpr size_t WS_UNITS = WGP_OFF  + (size_t)3 * R_ * D_ / 4; // 6291456 slots
constexpr size_t WS_BYTES = WS_UNITS * 16;                      // 96 MiB

// PRECISE activations (round-0-verified). Do NOT substitute fast approximations:
// the spike-subtract at 0.5 is a discontinuity -- any epsilon of extra numeric
// error flips elements across it for a 0.5-sized absmax (round-1 post-mortem).
__device__ __forceinline__ float sigmoidf_(float x) { return 1.0f / (1.0f + expf(-x)); }

// Raw workgroup barrier: waits LDS ops only (lgkmcnt), NOT vmcnt -> the register
// prefetch loads stay in flight across the barrier (T4-lite). sched_barrier(0)
// fences both sides so ds ops / reg-only MFMAs can't migrate across (rule #18).
__device__ __forceinline__ void wg_barrier() {
    __builtin_amdgcn_sched_barrier(0);
    asm volatile("s_waitcnt lgkmcnt(0)" ::: "memory");
    __builtin_amdgcn_s_barrier();
    __builtin_amdgcn_sched_barrier(0);
}

// Streaming pre-pack: fp32 -> {fp16 hi | fp16 lo} 16B slots, one slot/thread.
// RTN casts -- bit-identical numerics to the in-kernel conversion it replaces.
__global__ __launch_bounds__(256)
void pack_planes(const float* __restrict__ X, const float* __restrict__ P,
                 const float* __restrict__ Win, const float* __restrict__ Wres,
                 const float* __restrict__ Wg, f32x4* __restrict__ ws)
{
    size_t gid = (size_t)blockIdx.x * 256 + threadIdx.x;
    if (gid >= WS_UNITS) return;
    const float* src;
    if (gid < PP_OFF) {
        src = X + gid * 4;                          // linear
    } else if (gid < WINP_OFF) {
        size_t s = gid - PP_OFF;                    // P: strided, first R cols
        src = P + (s >> 9) * MAXD + (s & 511) * 4;  // R_/4 = 512 slots/row
    } else if (gid < WRESP_OFF) {
        src = Win + (gid - WINP_OFF) * 4;           // linear
    } else if (gid < WGP_OFF) {
        src = Wres + (gid - WRESP_OFF) * 4;         // linear
    } else {
        src = Wg + (gid - WGP_OFF) * 4;             // linear
    }
    f32x4 v = *(const f32x4*)src;
    half4 h, l;
    #pragma unroll
    for (int j = 0; j < 4; ++j) {
        h[j] = (_Float16)v[j];
        l[j] = (_Float16)(v[j] - (float)h[j]);
    }
    f32x4 o;
    ((half4*)&o)[0] = h;
    ((half4*)&o)[1] = l;
    ws[gid] = o;
}

// Fused: pre = X*Win^T + prev*Wres^T (K=3072), gates = X*Wgate^T (K=1024, 3 sets),
// state = o*( 0.9*f*prev + 0.1*tanh(i*pre) ), spike-subtract, fp32 store.
//
// Numerics: 3-term fp16 split (hh + lh + hl, lo*lo dropped) -- state error ~1e-7,
// verified zero threshold-flips (absmax = 1 bf16 ulp). 2-term (~1e-4) flipped
// hundreds of elements across the 0.5 spike threshold (round-1 post-mortem).
//
// PACKED=true: hi/lo planes come pre-split from workspace (pack_planes) --
// removes the 32x-redundant cvt chain (~40% of round-2 VALU). PACKED=false is
// the round-2 kernel verbatim (fallback when ws_size < WS_BYTES).
//
// LDS is FRAGMENT-MAJOR with XOR swizzle: element (r,k) of a 16-row group at
// half-index ((r&15)^q)*8 + q*128 + (k&7), q = k>>3. Frag reads conflict-free;
// staging writes spread over 16 banks (round-2 verified: conflicts halved).
template<bool PACKED>
__global__ __launch_bounds__(256, 2)
void reservoir_fused(const float* __restrict__ X,     // B x D
                     const float* __restrict__ P,     // B x MAXD (use first R cols)
                     const float* __restrict__ Win,   // R x D
                     const float* __restrict__ Wres,  // R x R
                     const float* __restrict__ Wg,    // 3R x D
                     const f32x4* __restrict__ ws,    // packed planes (PACKED only)
                     float* __restrict__ out)         // B x MAXD
{
    __shared__ _Float16 sA[2][8][512];      // [hi/lo][rowgroup16][frag halves] 16 KB
    __shared__ _Float16 sW[2][4][4][512];   // [hi/lo][set][colgroup][...]      32 KB

    const int tid  = threadIdx.x;
    const int lane = tid & 63;
    const int wv   = tid >> 6;                      // wave id 0..3
    const int m0   = blockIdx.y * BM;
    const int n0   = blockIdx.x * BN;

    f32x4 acc[4][2][4];                              // [set][mtile][ntile]
    #pragma unroll
    for (int s = 0; s < 4; ++s)
        #pragma unroll
        for (int mt = 0; mt < 2; ++mt)
            #pragma unroll
            for (int nt = 0; nt < 4; ++nt) acc[s][mt][nt] = (f32x4){0.f, 0.f, 0.f, 0.f};

    // staging coordinates: thread covers (row = crow + 32i, k = c4..c4+3)
    const int crow = tid >> 3;            // 0..31
    const int c4   = (tid & 7) * 4;       // 0,4,...,28
    const int q    = c4 >> 3;             // k-octet 0..3
    const int fbase = q * 128 + (c4 & 4); // swizzled half-offset base

    // frag read offset for this lane (halves)
    const int raddr = ((((lane & 15) ^ (lane >> 4)) << 3) + ((lane >> 4) << 7));

    // register prefetch buffers (next chunk)
    f32x4 pa[4];                          // A tile: 128 rows
    f32x4 pw[8];                          // [0..1]=pre W, [2..7]=gate W (phase1 only)

    auto issue_loads = [&](int t) {
        if (t < NCH1) {
            const int kc = t * BK + c4;
            if constexpr (PACKED) {
                const int kq = kc >> 2;
                const f32x4* a = ws + XP_OFF + (size_t)(m0 + crow) * (D_ / 4) + kq;
                #pragma unroll
                for (int i = 0; i < 4; ++i) pa[i] = a[(size_t)(32 * i) * (D_ / 4)];
                const f32x4* w = ws + WINP_OFF + (size_t)(n0 + crow) * (D_ / 4) + kq;
                #pragma unroll
                for (int i = 0; i < 2; ++i) pw[i] = w[(size_t)(32 * i) * (D_ / 4)];
                const f32x4* g = ws + WGP_OFF + (size_t)(n0 + crow) * (D_ / 4) + kq;
                #pragma unroll
                for (int gg = 0; gg < 3; ++gg)
                    #pragma unroll
                    for (int i = 0; i < 2; ++i)
                        pw[2 + gg * 2 + i] = g[(size_t)(gg * R_ + 32 * i) * (D_ / 4)];
            } else {
                const float* a = X + (size_t)m0 * D_ + kc;
                #pragma unroll
                for (int i = 0; i < 4; ++i)
                    pa[i] = *(const f32x4*)(a + (size_t)(crow + 32 * i) * D_);
                const float* w = Win + (size_t)n0 * D_ + kc;
                #pragma unroll
                for (int i = 0; i < 2; ++i)
                    pw[i] = *(const f32x4*)(w + (size_t)(crow + 32 * i) * D_);
                const float* g = Wg + (size_t)n0 * D_ + kc;
                #pragma unroll
                for (int gg = 0; gg < 3; ++gg)
                    #pragma unroll
                    for (int i = 0; i < 2; ++i)
                        pw[2 + gg * 2 + i] = *(const f32x4*)(g + (size_t)(gg * R_ + crow + 32 * i) * D_);
            }
        } else {
            const int kc = t * BK - D_ + c4;
            if constexpr (PACKED) {
                const int kq = kc >> 2;
                const f32x4* a = ws + PP_OFF + (size_t)(m0 + crow) * (R_ / 4) + kq;
                #pragma unroll
                for (int i = 0; i < 4; ++i) pa[i] = a[(size_t)(32 * i) * (R_ / 4)];
                const f32x4* w = ws + WRESP_OFF + (size_t)(n0 + crow) * (R_ / 4) + kq;
                #pragma unroll
                for (int i = 0; i < 2; ++i) pw[i] = w[(size_t)(32 * i) * (R_ / 4)];
            } else {
                const float* a = P + (size_t)m0 * MAXD + kc;
                #pragma unroll
                for (int i = 0; i < 4; ++i)
                    pa[i] = *(const f32x4*)(a + (size_t)(crow + 32 * i) * MAXD);
                const float* w = Wres + (size_t)n0 * R_ + kc;
                #pragma unroll
                for (int i = 0; i < 2; ++i)
                    pw[i] = *(const f32x4*)(w + (size_t)(crow + 32 * i) * R_);
            }
        }
    };

    auto stage_A = [&]() {
        #pragma unroll
        for (int i = 0; i < 4; ++i) {
            const int r = crow + 32 * i;
            const int idx = (((r & 15) ^ q) << 3) + fbase;
            if constexpr (PACKED) {
                f32x4 v = pa[i];
                *(f32x2*)(&sA[0][r >> 4][idx]) = (f32x2){v.x, v.y};   // hi half4
                *(f32x2*)(&sA[1][r >> 4][idx]) = (f32x2){v.z, v.w};   // lo half4
            } else {
                half4 h, l;
                #pragma unroll
                for (int j = 0; j < 4; ++j) {
                    float v = pa[i][j];
                    h[j] = (_Float16)v;
                    l[j] = (_Float16)(v - (float)h[j]);
                }
                *(half4*)(&sA[0][r >> 4][idx]) = h;
                *(half4*)(&sA[1][r >> 4][idx]) = l;
            }
        }
    };
    auto stage_W = [&](int nw) {   // nw = 8 (phase1) or 2 (phase2); literal at call site
        #pragma unroll
        for (int i = 0; i < 8; ++i) if (i < nw) {
            const int s   = (i < 2) ? 0 : 1 + ((i - 2) >> 1);
            const int sub = (i < 2) ? i : ((i - 2) & 1);
            const int r   = crow + 32 * sub;
            const int idx = (((r & 15) ^ q) << 3) + fbase;
            if constexpr (PACKED) {
                f32x4 v = pw[i];
                *(f32x2*)(&sW[0][s][r >> 4][idx]) = (f32x2){v.x, v.y};
                *(f32x2*)(&sW[1][s][r >> 4][idx]) = (f32x2){v.z, v.w};
            } else {
                half4 h, l;
                #pragma unroll
                for (int j = 0; j < 4; ++j) {
                    float v = pw[i][j];
                    h[j] = (_Float16)v;
                    l[j] = (_Float16)(v - (float)h[j]);
                }
                *(half4*)(&sW[0][s][r >> 4][idx]) = h;
                *(half4*)(&sW[1][s][r >> 4][idx]) = l;
            }
        }
    };

#define MFMA_BLOCK(NSETS)                                                                         \
    {                                                                                             \
        half8 ah0 = *(const half8*)(&sA[0][wv * 2 + 0][raddr]);                                   \
        half8 al0 = *(const half8*)(&sA[1][wv * 2 + 0][raddr]);                                   \
        half8 ah1 = *(const half8*)(&sA[0][wv * 2 + 1][raddr]);                                   \
        half8 al1 = *(const half8*)(&sA[1][wv * 2 + 1][raddr]);                                   \
        __builtin_amdgcn_s_setprio(1);                                                            \
        _Pragma("unroll")                                                                         \
        for (int s = 0; s < NSETS; ++s) {                                                         \
            _Pragma("unroll")                                                                     \
            for (int nt = 0; nt < 4; ++nt) {                                                      \
                half8 bh = *(const half8*)(&sW[0][s][nt][raddr]);                                 \
                half8 bl = *(const half8*)(&sW[1][s][nt][raddr]);                                 \
                acc[s][0][nt] = __builtin_amdgcn_mfma_f32_16x16x32_f16(ah0, bh, acc[s][0][nt], 0, 0, 0); \
                acc[s][0][nt] = __builtin_amdgcn_mfma_f32_16x16x32_f16(al0, bh, acc[s][0][nt], 0, 0, 0); \
                acc[s][0][nt] = __builtin_amdgcn_mfma_f32_16x16x32_f16(ah0, bl, acc[s][0][nt], 0, 0, 0); \
                acc[s][1][nt] = __builtin_amdgcn_mfma_f32_16x16x32_f16(ah1, bh, acc[s][1][nt], 0, 0, 0); \
                acc[s][1][nt] = __builtin_amdgcn_mfma_f32_16x16x32_f16(al1, bh, acc[s][1][nt], 0, 0, 0); \
                acc[s][1][nt] = __builtin_amdgcn_mfma_f32_16x16x32_f16(ah1, bl, acc[s][1][nt], 0, 0, 0); \
            }                                                                                     \
        }                                                                                         \
        __builtin_amdgcn_s_setprio(0);                                                            \
    }

    issue_loads(0);

    // Phase 1: k in [0, D) -- X vs {Win, Wg i/f/o}
    #pragma unroll 1
    for (int t = 0; t < NCH1; ++t) {
        stage_A();
        stage_W(8);
        issue_loads(t + 1);      // prefetch stays in flight across both barriers
        wg_barrier();            // writes visible
        MFMA_BLOCK(4)
        wg_barrier();            // reads done before next writes
    }
    // Phase 2: k in [D, D+R) -- prev vs Wres (pre set only)
    #pragma unroll 1
    for (int t = NCH1; t < NCHUNK; ++t) {
        stage_A();
        stage_W(2);
        if (t + 1 < NCHUNK) issue_loads(t + 1);
        wg_barrier();
        MFMA_BLOCK(1)
        wg_barrier();
    }
#undef MFMA_BLOCK

    // ---- epilogue: C/D layout col=lane&15, row=quad*4+reg (m89-verified) ----
    const int fr = lane & 15;
    const int qd = lane >> 4;
    #pragma unroll
    for (int mt = 0; mt < 2; ++mt)
        #pragma unroll
        for (int nt = 0; nt < 4; ++nt)
            #pragma unroll
            for (int r = 0; r < 4; ++r) {
                int row = m0 + wv * 32 + mt * 16 + qd * 4 + r;   // batch index
                int col = n0 + nt * 16 + fr;                      // reservoir index
                float pre = acc[0][mt][nt][r];
                float ig  = sigmoidf_(acc[1][mt][nt][r]);
                float fg  = sigmoidf_(acc[2][mt][nt][r]);
                float og  = sigmoidf_(acc[3][mt][nt][r]);
                float pv  = P[(size_t)row * MAXD + col];          // exact fp32 prev
                float st  = 0.9f * (fg * pv) + 0.1f * tanhf(ig * pre);
                st *= og;
                if (st > 0.5f) st -= 0.5f;
                out[(size_t)row * MAXD + col] = st;
            }
}

// Zero the pad region out[:, 2048:2560] (harness poisons d_out with 0xAA).
__global__ void pad_zero(float* __restrict__ out) {
    int idx = blockIdx.x * 256 + threadIdx.x;
    int row = idx >> 7;
    int c   = (idx & 127) * 4;
    *(f32x4*)(&out[(size_t)row * MAXD + R_ + c]) = (f32x4){0.f, 0.f, 0.f, 0.f};
}

extern "C" void kernel_launch(void* const* d_in, const int* in_sizes, int n_in,
                              void* d_out, int out_size, void* d_ws, size_t ws_size,
                              hipStream_t stream) {
    const float* X    = (const float*)d_in[0];
    const float* P    = (const float*)d_in[1];
    const float* Win  = (const float*)d_in[2];
    const float* Wres = (const float*)d_in[3];
    const float* Wg   = (const float*)d_in[4];
    float* out        = (float*)d_out;

    pad_zero<<<2048, 256, 0, stream>>>(out);
    dim3 grid(R_ / BN, B_ / BM);   // (32, 32) = 1024 blocks

    if (d_ws != nullptr && ws_size >= WS_BYTES) {
        f32x4* ws = (f32x4*)d_ws;
        pack_planes<<<(int)(WS_UNITS / 256), 256, 0, stream>>>(X, P, Win, Wres, Wg, ws);
        reservoir_fused<true><<<grid, 256, 0, stream>>>(X, P, Win, Wres, Wg, ws, out);
    } else {
        reservoir_fused<false><<<grid, 256, 0, stream>>>(X, P, Win, Wres, Wg, nullptr, out);
    }
}

// Round 4
// 441.628 us; speedup vs baseline: 1.0290x; 1.0290x over previous
//
#include <hip/hip_runtime.h>

// Problem constants
#define B_  4096
#define D_  1024
#define R_  2048
#define MAXD 2560

typedef _Float16 half8 __attribute__((ext_vector_type(8)));  // 8 fp16 = 4 VGPRs (MFMA frag)
typedef _Float16 half4 __attribute__((ext_vector_type(4)));  // 8-byte LDS store
typedef float    f32x4 __attribute__((ext_vector_type(4)));
typedef float    f32x2 __attribute__((ext_vector_type(2)));

constexpr int BM = 128;      // M tile (batch rows)
constexpr int BN = 64;       // N tile (reservoir cols)
constexpr int BK = 32;       // K chunk (elems)
constexpr int NCH1 = D_ / BK;   // 32 phase-1 chunks (X vs Win+gates)
constexpr int NCH2 = R_ / BK;   // 64 phase-2 chunks (prev vs Wres)

// ---- packed hi/lo plane layout in workspace (units = 16B slots = 4 elems) ----
constexpr size_t XP_OFF   = 0;                                  // B x D
constexpr size_t PP_OFF   = XP_OFF   + (size_t)B_ * D_ / 4;     // B x R (first R cols of P)
constexpr size_t WINP_OFF = PP_OFF   + (size_t)B_ * R_ / 4;     // R x D
constexpr size_t WRESP_OFF= WINP_OFF + (size_t)R_ * D_ / 4;     // R x R
constexpr size_t WGP_OFF  = WRESP_OFF+ (size_t)R_ * R_ / 4;     // 3R x D
constexpr size_t WS_UNITS = WGP_OFF  + (size_t)3 * R_ * D_ / 4; // 6291456 slots
constexpr size_t WS_BYTES = WS_UNITS * 16;                      // 96 MiB
constexpr size_t PAD_UNITS= (size_t)B_ * (MAXD - R_) / 4;       // 524288 pad slots

// PRECISE activations (round-0-verified). Do NOT substitute fast approximations:
// the spike-subtract at 0.5 is a discontinuity -- any epsilon of extra numeric
// error flips elements across it for a 0.5-sized absmax (round-1 post-mortem).
__device__ __forceinline__ float sigmoidf_(float x) { return 1.0f / (1.0f + expf(-x)); }

// lgkm-only workgroup barrier: prefetch global loads stay in flight across it.
// sched_barrier(0) fences both sides (rule #18: MFMAs must not hoist past the
// lgkmcnt wait; ds ops must not migrate across the s_barrier).
__device__ __forceinline__ void wg_barrier() {
    __builtin_amdgcn_sched_barrier(0);
    asm volatile("s_waitcnt lgkmcnt(0)" ::: "memory");
    __builtin_amdgcn_s_barrier();
    __builtin_amdgcn_sched_barrier(0);
}

// Streaming pre-pack (fp32 -> {fp16 hi | fp16 lo} 16B slots, RTN -- bit-identical
// to the in-kernel conversion it replaces) fused with the out[:,R:] pad-zero.
__global__ __launch_bounds__(256)
void prep(const float* __restrict__ X, const float* __restrict__ P,
          const float* __restrict__ Win, const float* __restrict__ Wres,
          const float* __restrict__ Wg, f32x4* __restrict__ ws,
          float* __restrict__ out)
{
    size_t gid = (size_t)blockIdx.x * 256 + threadIdx.x;
    if (gid < WS_UNITS) {
        const float* src;
        if (gid < PP_OFF) {
            src = X + gid * 4;
        } else if (gid < WINP_OFF) {
            size_t s = gid - PP_OFF;                    // P: strided, first R cols
            src = P + (s >> 9) * MAXD + (s & 511) * 4;  // R_/4 = 512 slots/row
        } else if (gid < WRESP_OFF) {
            src = Win + (gid - WINP_OFF) * 4;
        } else if (gid < WGP_OFF) {
            src = Wres + (gid - WRESP_OFF) * 4;
        } else {
            src = Wg + (gid - WGP_OFF) * 4;
        }
        f32x4 v = *(const f32x4*)src;
        half4 h, l;
        #pragma unroll
        for (int j = 0; j < 4; ++j) {
            h[j] = (_Float16)v[j];
            l[j] = (_Float16)(v[j] - (float)h[j]);
        }
        f32x4 o;
        ((half4*)&o)[0] = h;
        ((half4*)&o)[1] = l;
        ws[gid] = o;
    } else {
        size_t p = gid - WS_UNITS;                      // pad: out[:, R_:MAXD] = 0
        size_t row = p >> 7;                            // 128 slots/row
        size_t c   = (p & 127) * 4;
        *(f32x4*)(out + row * MAXD + R_ + c) = (f32x4){0.f, 0.f, 0.f, 0.f};
    }
}

// Fused: pre = X*Win^T + prev*Wres^T (K=3072), gates = X*Wgate^T (K=1024, 3 sets),
// state = o*( 0.9*f*prev + 0.1*tanh(i*pre) ), spike-subtract, fp32 store.
//
// Numerics: 3-term fp16 split (hh + lh + hl) -- state error ~1e-7, zero
// threshold-flips. 2-term (~1e-4) flipped hundreds across the 0.5 spike
// threshold (round-1 post-mortem). PACKED: planes pre-split by prep().
//
// LDS (48 KB flat, half-indexed):
//  phase 1 (single-buffered, 2 barriers/chunk, 96 MFMAs/chunk/wave):
//    A_hi grp g: g*512          (8 grps)    A_lo: +4096
//    W_hi[s][g]: 8192+s*2048+g*512 (4 sets) W_lo: +8192
//  phase 2 (DOUBLE-buffered, 1 lgkm-barrier/chunk): buffer b at b*12288:
//    A_hi: +0 (8 grps)  A_lo: +4096  W_hi: +8192+g*512 (4 grps)  W_lo: +2048 rel
//  WAR safety: buf[t&1]'s previous reader is MFMA(t-2), whose ds_reads drained
//  at barrier(t-1) (lgkmcnt(0) before s_barrier) -> stage(t) cannot race it.
//
// Within-group swizzle: elem (r,k) at ((r&15)^q)*8 + q*128 + (k&7), q=k>>3.
// Frag reads are a perfect bank permutation (conflict-free); 8B staging writes
// land ~2 accesses/bank (free per m136).
template<bool PACKED>
__global__ __launch_bounds__(256, 2)
void reservoir_fused(const float* __restrict__ X,     // B x D
                     const float* __restrict__ P,     // B x MAXD (use first R cols)
                     const float* __restrict__ Win,   // R x D
                     const float* __restrict__ Wres,  // R x R
                     const float* __restrict__ Wg,    // 3R x D
                     const f32x4* __restrict__ ws,    // packed planes (PACKED only)
                     float* __restrict__ out)         // B x MAXD
{
    __shared__ _Float16 smem[24576];                  // 48 KB

    const int tid  = threadIdx.x;
    const int lane = tid & 63;
    const int wv   = tid >> 6;                        // wave id 0..3
    const int m0   = blockIdx.y * BM;
    const int n0   = blockIdx.x * BN;

    f32x4 acc[4][2][4];                               // [set][mtile][ntile]
    #pragma unroll
    for (int s = 0; s < 4; ++s)
        #pragma unroll
        for (int mt = 0; mt < 2; ++mt)
            #pragma unroll
            for (int nt = 0; nt < 4; ++nt) acc[s][mt][nt] = (f32x4){0.f, 0.f, 0.f, 0.f};

    // staging coordinates: thread covers (row = crow + 32i, k = c4..c4+3)
    const int crow = tid >> 3;            // 0..31
    const int c4   = (tid & 7) * 4;       // 0,4,...,28
    const int q    = c4 >> 3;             // k-octet 0..3
    const int swz  = (((crow & 15) ^ q) << 3) + q * 128 + (c4 & 4);
    const int grpb = (crow >> 4) * 512;   // rowgroup base (0 or 512)
    const int aw   = grpb + swz;          // A write base; +i*1024 per 32-row step
    const int ww   = 8192 + grpb + swz;   // phase-1 W write base; +s*2048+sub*1024

    // frag read offset for this lane (halves, within a 512-half group)
    const int raddr = (((lane & 15) ^ (lane >> 4)) << 3) + ((lane >> 4) << 7);

    // register prefetch buffers (next chunk)
    f32x4 pa[4];                          // A tile: 128 rows
    f32x4 pw[8];                          // [0..1]=pre W, [2..7]=gate W (phase1 only)

    // pointer-bumped global bases (one address setup, immediate-strided loads)
    const f32x4 *aX = nullptr, *wI = nullptr, *wG = nullptr, *aP = nullptr, *wR = nullptr;
    const float *fX = nullptr, *fI = nullptr, *fG = nullptr, *fP = nullptr, *fR = nullptr;
    if constexpr (PACKED) {
        const int sl = c4 >> 2;
        aX = ws + XP_OFF    + (size_t)(m0 + crow) * (D_ / 4) + sl;
        wI = ws + WINP_OFF  + (size_t)(n0 + crow) * (D_ / 4) + sl;
        wG = ws + WGP_OFF   + (size_t)(n0 + crow) * (D_ / 4) + sl;
        aP = ws + PP_OFF    + (size_t)(m0 + crow) * (R_ / 4) + sl;
        wR = ws + WRESP_OFF + (size_t)(n0 + crow) * (R_ / 4) + sl;
    } else {
        fX = X    + (size_t)(m0 + crow) * D_   + c4;
        fI = Win  + (size_t)(n0 + crow) * D_   + c4;
        fG = Wg   + (size_t)(n0 + crow) * D_   + c4;
        fP = P    + (size_t)(m0 + crow) * MAXD + c4;
        fR = Wres + (size_t)(n0 + crow) * R_   + c4;
    }

    auto ld1 = [&](int t) {
        if constexpr (PACKED) {
            const size_t o = (size_t)t * 8;
            #pragma unroll
            for (int i = 0; i < 4; ++i) pa[i] = aX[o + (size_t)(32 * i) * (D_ / 4)];
            #pragma unroll
            for (int i = 0; i < 2; ++i) pw[i] = wI[o + (size_t)(32 * i) * (D_ / 4)];
            #pragma unroll
            for (int g = 0; g < 3; ++g)
                #pragma unroll
                for (int i = 0; i < 2; ++i)
                    pw[2 + g * 2 + i] = wG[o + (size_t)(g * R_ + 32 * i) * (D_ / 4)];
        } else {
            const size_t o = (size_t)t * BK;
            #pragma unroll
            for (int i = 0; i < 4; ++i) pa[i] = *(const f32x4*)(fX + o + (size_t)(32 * i) * D_);
            #pragma unroll
            for (int i = 0; i < 2; ++i) pw[i] = *(const f32x4*)(fI + o + (size_t)(32 * i) * D_);
            #pragma unroll
            for (int g = 0; g < 3; ++g)
                #pragma unroll
                for (int i = 0; i < 2; ++i)
                    pw[2 + g * 2 + i] = *(const f32x4*)(fG + o + (size_t)(g * R_ + 32 * i) * D_);
        }
    };
    auto ld2 = [&](int t) {   // t = phase-2 chunk 0..NCH2-1
        if constexpr (PACKED) {
            const size_t o = (size_t)t * 8;
            #pragma unroll
            for (int i = 0; i < 4; ++i) pa[i] = aP[o + (size_t)(32 * i) * (R_ / 4)];
            #pragma unroll
            for (int i = 0; i < 2; ++i) pw[i] = wR[o + (size_t)(32 * i) * (R_ / 4)];
        } else {
            const size_t o = (size_t)t * BK;
            #pragma unroll
            for (int i = 0; i < 4; ++i) pa[i] = *(const f32x4*)(fP + o + (size_t)(32 * i) * MAXD);
            #pragma unroll
            for (int i = 0; i < 2; ++i) pw[i] = *(const f32x4*)(fR + o + (size_t)(32 * i) * R_);
        }
    };

    auto cvt_store = [&](int off_h, int off_l, f32x4 v) {
        if constexpr (PACKED) {
            *(f32x2*)&smem[off_h] = (f32x2){v.x, v.y};   // pre-split hi half4
            *(f32x2*)&smem[off_l] = (f32x2){v.z, v.w};   // pre-split lo half4
        } else {
            half4 h, l;
            #pragma unroll
            for (int j = 0; j < 4; ++j) {
                h[j] = (_Float16)v[j];
                l[j] = (_Float16)(v[j] - (float)h[j]);
            }
            *(half4*)&smem[off_h] = h;
            *(half4*)&smem[off_l] = l;
        }
    };

    auto stA = [&](int base) {
        #pragma unroll
        for (int i = 0; i < 4; ++i)
            cvt_store(base + aw + i * 1024, base + aw + i * 1024 + 4096, pa[i]);
    };
    auto stW1 = [&]() {
        #pragma unroll
        for (int i = 0; i < 8; ++i) {
            const int s   = (i < 2) ? 0 : 1 + ((i - 2) >> 1);
            const int sub = (i < 2) ? i : ((i - 2) & 1);
            const int off = ww + s * 2048 + sub * 1024;
            cvt_store(off, off + 8192, pw[i]);
        }
    };
    auto stW2 = [&](int base) {
        #pragma unroll
        for (int i = 0; i < 2; ++i) {
            const int off = base + 8192 + grpb + i * 1024 + swz;
            cvt_store(off, off + 2048, pw[i]);
        }
    };

// AB = A-plane base, WB = W hi base, WLD = W lo delta, NSETS = gate sets
#define MFMA_BLK(AB, WB, WLD, NSETS)                                                              \
    {                                                                                             \
        half8 ah0 = *(const half8*)&smem[(AB) + (wv * 2 + 0) * 512 + raddr];                      \
        half8 al0 = *(const half8*)&smem[(AB) + (wv * 2 + 0) * 512 + raddr + 4096];               \
        half8 ah1 = *(const half8*)&smem[(AB) + (wv * 2 + 1) * 512 + raddr];                      \
        half8 al1 = *(const half8*)&smem[(AB) + (wv * 2 + 1) * 512 + raddr + 4096];               \
        __builtin_amdgcn_s_setprio(1);                                                            \
        _Pragma("unroll")                                                                         \
        for (int s = 0; s < NSETS; ++s) {                                                         \
            _Pragma("unroll")                                                                     \
            for (int nt = 0; nt < 4; ++nt) {                                                      \
                half8 bh = *(const half8*)&smem[(WB) + s * 2048 + nt * 512 + raddr];              \
                half8 bl = *(const half8*)&smem[(WB) + s * 2048 + nt * 512 + raddr + (WLD)];      \
                acc[s][0][nt] = __builtin_amdgcn_mfma_f32_16x16x32_f16(ah0, bh, acc[s][0][nt], 0, 0, 0); \
                acc[s][0][nt] = __builtin_amdgcn_mfma_f32_16x16x32_f16(al0, bh, acc[s][0][nt], 0, 0, 0); \
                acc[s][0][nt] = __builtin_amdgcn_mfma_f32_16x16x32_f16(ah0, bl, acc[s][0][nt], 0, 0, 0); \
                acc[s][1][nt] = __builtin_amdgcn_mfma_f32_16x16x32_f16(ah1, bh, acc[s][1][nt], 0, 0, 0); \
                acc[s][1][nt] = __builtin_amdgcn_mfma_f32_16x16x32_f16(al1, bh, acc[s][1][nt], 0, 0, 0); \
                acc[s][1][nt] = __builtin_amdgcn_mfma_f32_16x16x32_f16(ah1, bl, acc[s][1][nt], 0, 0, 0); \
            }                                                                                     \
        }                                                                                         \
        __builtin_amdgcn_s_setprio(0);                                                            \
    }

    ld1(0);

    // ---- Phase 1: X vs {Win, gates}; single-buffered, 2 barriers/chunk ----
    #pragma unroll 1
    for (int t = 0; t < NCH1 - 1; ++t) {
        stA(0); stW1();
        ld1(t + 1);              // prefetch in flight across both barriers
        wg_barrier();            // writes visible
        MFMA_BLK(0, 8192, 8192, 4)
        wg_barrier();            // reads done before next chunk's writes
    }
    {   // peeled last phase-1 chunk: prefetch phase-2 chunk 0
        stA(0); stW1();
        ld2(0);
        wg_barrier();
        MFMA_BLK(0, 8192, 8192, 4)
        wg_barrier();            // all phase-1 reads drained -> layout reuse safe
    }

    // ---- Phase 2: prev vs Wres; double-buffered, ONE lgkm barrier/chunk ----
    #pragma unroll 1
    for (int t = 0; t < NCH2 - 1; ++t) {
        const int base = (t & 1) * 12288;
        stA(base); stW2(base);   // write buf[t&1]; overlaps other waves' MFMA(t-1)
        ld2(t + 1);
        wg_barrier();
        MFMA_BLK(base, base + 8192, 2048, 1)   // no trailing barrier
    }
    {   // peeled last phase-2 chunk
        const int base = ((NCH2 - 1) & 1) * 12288;
        stA(base); stW2(base);
        wg_barrier();
        MFMA_BLK(base, base + 8192, 2048, 1)
    }
#undef MFMA_BLK

    // ---- epilogue: C/D layout col=lane&15, row=quad*4+reg (m89-verified) ----
    const int fr = lane & 15;
    const int qd = lane >> 4;
    #pragma unroll
    for (int mt = 0; mt < 2; ++mt)
        #pragma unroll
        for (int nt = 0; nt < 4; ++nt)
            #pragma unroll
            for (int r = 0; r < 4; ++r) {
                int row = m0 + wv * 32 + mt * 16 + qd * 4 + r;   // batch index
                int col = n0 + nt * 16 + fr;                      // reservoir index
                float pre = acc[0][mt][nt][r];
                float ig  = sigmoidf_(acc[1][mt][nt][r]);
                float fg  = sigmoidf_(acc[2][mt][nt][r]);
                float og  = sigmoidf_(acc[3][mt][nt][r]);
                float pv  = P[(size_t)row * MAXD + col];          // exact fp32 prev
                float st  = 0.9f * (fg * pv) + 0.1f * tanhf(ig * pre);
                st *= og;
                if (st > 0.5f) st -= 0.5f;
                out[(size_t)row * MAXD + col] = st;
            }
}

// Fallback pad (no-workspace path only).
__global__ void pad_zero(float* __restrict__ out) {
    int idx = blockIdx.x * 256 + threadIdx.x;
    int row = idx >> 7;
    int c   = (idx & 127) * 4;
    *(f32x4*)(&out[(size_t)row * MAXD + R_ + c]) = (f32x4){0.f, 0.f, 0.f, 0.f};
}

extern "C" void kernel_launch(void* const* d_in, const int* in_sizes, int n_in,
                              void* d_out, int out_size, void* d_ws, size_t ws_size,
                              hipStream_t stream) {
    const float* X    = (const float*)d_in[0];
    const float* P    = (const float*)d_in[1];
    const float* Win  = (const float*)d_in[2];
    const float* Wres = (const float*)d_in[3];
    const float* Wg   = (const float*)d_in[4];
    float* out        = (float*)d_out;

    dim3 grid(R_ / BN, B_ / BM);   // (32, 32) = 1024 blocks

    if (d_ws != nullptr && ws_size >= WS_BYTES) {
        f32x4* ws = (f32x4*)d_ws;
        prep<<<(int)((WS_UNITS + PAD_UNITS) / 256), 256, 0, stream>>>(X, P, Win, Wres, Wg, ws, out);
        reservoir_fused<true><<<grid, 256, 0, stream>>>(X, P, Win, Wres, Wg, ws, out);
    } else {
        pad_zero<<<2048, 256, 0, stream>>>(out);
        reservoir_fused<false><<<grid, 256, 0, stream>>>(X, P, Win, Wres, Wg, nullptr, out);
    }
}

// Round 6
// 421.886 us; speedup vs baseline: 1.0772x; 1.0468x over previous
//
#include <hip/hip_runtime.h>
#include <stdint.h>

// Problem constants
#define B_  4096
#define D_  1024
#define R_  2048
#define MAXD 2560

typedef _Float16 half8 __attribute__((ext_vector_type(8)));  // 8 fp16 = 4 VGPRs (MFMA frag)
typedef _Float16 half4 __attribute__((ext_vector_type(4)));
typedef float    f32x4 __attribute__((ext_vector_type(4)));

constexpr int BM = 128;      // M tile (batch rows)
constexpr int BN = 64;       // N tile (reservoir cols)
constexpr int BK = 32;       // K chunk (elems)
constexpr int NCH1 = D_ / BK;   // 32 phase-1 chunks (X vs Win+gates)
constexpr int NCH2 = R_ / BK;   // 64 phase-2 chunks (prev vs Wres)

// ---- ws layout: MFMA-fragment chunks ------------------------------------
// chunk(rowgrp, kb, pl) = 512 halves (1 KiB). halves[l*8 + j] =
//   plane_pl( M[rowgrp*16 + (l&15)][kb*32 + (l>>4)*8 + j] )
// pl=0: fp16 hi (RTN cast), pl=1: fp16 lo (residual). This is exactly the
// 16x16x32 MFMA A/B lane mapping (row/col = l&15, k = (l>>4)*8+j), verified
// by rounds 0-4's working LDS read pattern. Chunk-pair (pl0,pl1) adjacent.
constexpr size_t XF_OFF  = 0;                                  // 256rg x 32kb
constexpr size_t PF_OFF  = XF_OFF  + (size_t)256 * 32 * 2 * 512;
constexpr size_t WIF_OFF = PF_OFF  + (size_t)256 * 64 * 2 * 512;   // Win: 128ng x 32kb
constexpr size_t WRF_OFF = WIF_OFF + (size_t)128 * 32 * 2 * 512;   // Wres: 128ng x 64kb
constexpr size_t WGF_OFF = WRF_OFF + (size_t)128 * 64 * 2 * 512;   // Wg: 384ng x 32kb
constexpr size_t WS_HALVES = WGF_OFF + (size_t)384 * 32 * 2 * 512; // 50,331,648
constexpr size_t WS_BYTES  = WS_HALVES * 2;                        // 96 MiB (same as r3/r4)
constexpr int NPACK_WTASKS = 49152;   // one wave-task per chunk-pair
constexpr int NPAD_WTASKS  = 8192;    // out[:,2048:2560] zero, 1 KiB per wave-task

// PRECISE activations (round-0-verified). Do NOT substitute fast approximations:
// the spike-subtract at 0.5 is a discontinuity -- any epsilon of extra numeric
// error flips elements across it for a 0.5-sized absmax (round-1 post-mortem).
__device__ __forceinline__ float sigmoidf_(float x) { return 1.0f / (1.0f + expf(-x)); }

// global -> LDS DMA, 16 B per lane. LDS dest is wave-uniform base + lane*16 (HW);
// global src is per-lane (base + lane*16 here).
__device__ __forceinline__ void gload_lds16(const _Float16* g, _Float16* l) {
    typedef const uint32_t __attribute__((address_space(1)))* gp_t;
    typedef uint32_t __attribute__((address_space(3)))* lp_t;
    __builtin_amdgcn_global_load_lds((gp_t)(const void*)g, (lp_t)(void*)l, 16, 0, 0);
}

// ---- prep: repack fp32 operands into hi/lo fragment chunks + pad-zero ----
// One wave per chunk-pair: lane reads 8 consecutive fp32 (32 B contiguous),
// RTN-splits (bit-identical to the in-kernel conversion rounds 0-4 used),
// writes hi 16 B + lo 16 B, both perfectly coalesced.
__global__ __launch_bounds__(256)
void prep(const float* __restrict__ X, const float* __restrict__ P,
          const float* __restrict__ Win, const float* __restrict__ Wres,
          const float* __restrict__ Wg, _Float16* __restrict__ ws,
          float* __restrict__ out)
{
    const int l = threadIdx.x & 63;
    const int wtask = blockIdx.x * 4 + (threadIdx.x >> 6);
    if (wtask < NPACK_WTASKS) {
        const float* src; int ld, rg, kb;
        int cp = wtask;
        if (cp < 8192)       {              src = X;    ld = D_;   rg = cp >> 5; kb = cp & 31; }
        else if (cp < 24576) { cp -= 8192;  src = P;    ld = MAXD; rg = cp >> 6; kb = cp & 63; }
        else if (cp < 28672) { cp -= 24576; src = Win;  ld = D_;   rg = cp >> 5; kb = cp & 31; }
        else if (cp < 36864) { cp -= 28672; src = Wres; ld = R_;   rg = cp >> 6; kb = cp & 63; }
        else                 { cp -= 36864; src = Wg;   ld = D_;   rg = cp >> 5; kb = cp & 31; }
        const float* s = src + (size_t)(rg * 16 + (l & 15)) * ld + kb * 32 + (l >> 4) * 8;
        f32x4 v0 = *(const f32x4*)s;
        f32x4 v1 = *(const f32x4*)(s + 4);
        half8 h, lo;
        #pragma unroll
        for (int j = 0; j < 4; ++j) {
            h[j]     = (_Float16)v0[j];  lo[j]     = (_Float16)(v0[j] - (float)h[j]);
            h[4 + j] = (_Float16)v1[j];  lo[4 + j] = (_Float16)(v1[j] - (float)h[4 + j]);
        }
        _Float16* dst = ws + (size_t)wtask * 1024;
        *(half8*)(dst + l * 8) = h;          // pl 0
        *(half8*)(dst + 512 + l * 8) = lo;   // pl 1
    } else {
        int p2 = wtask - NPACK_WTASKS;                 // 0..8191
        size_t idx = (size_t)p2 * 256 + l * 4;         // over 4096 x 512 pad region
        size_t row = idx >> 9, col = idx & 511;
        *(f32x4*)(out + row * MAXD + R_ + col) = (f32x4){0.f, 0.f, 0.f, 0.f};
    }
}

// ---- main fused kernel (packed path) -------------------------------------
// pre = X*Win^T + prev*Wres^T (K=3072), gates = X*Wgate^T (K=1024, 3 sets),
// state = o*( 0.9*f*prev + 0.1*tanh(i*pre) ), spike-subtract, fp32 store.
// 3-term fp16 split (hh+lh+hl), state error ~1e-7, zero threshold-flips.
//
// Structure (round-5): A fragments NEVER touch LDS (direct per-lane global
// loads, double-buffered in VGPRs); W staged via global_load_lds DMA into a
// double-buffered 64 KiB LDS; ONE barrier per chunk with counted
// `s_waitcnt vmcnt(4)` -- the 4 A loads (issued after the W DMAs, fenced by
// sched_barrier) may stay in flight, the W DMAs must have landed. W(t+1) is
// issued at the top of block t => one full MFMA block of latency hiding.
// Per-CU per-ph1-chunk: MFMA 3725 cyc vs LDS ~1500 (was ~4400) -> MFMA-bound.
__global__ __launch_bounds__(256, 2)
void reservoir_packed(const _Float16* __restrict__ ws,
                      const float* __restrict__ P,      // fp32 prev for epilogue
                      float* __restrict__ out)
{
    __shared__ _Float16 smem[32768];                    // 2 bufs x 16384 halves (64 KiB)

    const int tid  = threadIdx.x;
    const int lane = tid & 63;
    const int wv   = tid >> 6;                          // wave id 0..3
    const int m0   = blockIdx.y * BM;
    const int n0   = blockIdx.x * BN;
    const int lb   = lane * 8;                          // lane offset within chunk (halves)
    const int rgA  = (m0 >> 4) + wv * 2;                // this wave's A rowgroup base
    const int ng0  = n0 >> 4;                           // block's W colgroup base

    f32x4 acc[4][2][4];                                 // [set][mtile][ntile]
    #pragma unroll
    for (int s = 0; s < 4; ++s)
        #pragma unroll
        for (int mt = 0; mt < 2; ++mt)
            #pragma unroll
            for (int nt = 0; nt < 4; ++nt) acc[s][mt][nt] = (f32x4){0.f, 0.f, 0.f, 0.f};

    // W DMA: ph1 stages 32 KiB (32 chunks: 4 sets x 4 grps x 2 planes), 8/wave.
    // LDS layout per buffer: pl*8192 + (s*4+g)*512.
    auto dmaW1 = [&](int t, int buf) {
        #pragma unroll
        for (int i = 0; i < 8; ++i) {
            const int c = wv * 8 + i, pl = c >> 4, r = c & 15, s = r >> 2, g = r & 3;
            const size_t gh = (s == 0)
                ? WIF_OFF + ((size_t)((ng0 + g) * 32 + t) * 2 + pl) * 512
                : WGF_OFF + ((size_t)(((s - 1) * 128 + ng0 + g) * 32 + t) * 2 + pl) * 512;
            gload_lds16(ws + gh + lb, &smem[buf * 16384 + pl * 8192 + r * 512]);
        }
    };
    // ph2 stages 8 KiB (1 set x 4 grps x 2 planes), 2/wave.
    auto dmaW2 = [&](int t, int buf) {
        #pragma unroll
        for (int i = 0; i < 2; ++i) {
            const int c = wv * 2 + i, pl = c >> 2, g = c & 3;
            const size_t gh = WRF_OFF + ((size_t)((ng0 + g) * 64 + t) * 2 + pl) * 512;
            gload_lds16(ws + gh + lb, &smem[buf * 16384 + pl * 8192 + g * 512]);
        }
    };

// A fragment loads: named regs only (rule #20 -- no runtime-indexed reg arrays).
#define LDA(ROFF, KBS, T, H0, L0, H1, L1)                                                         \
    {                                                                                             \
        const _Float16* b0_ = ws + (ROFF) + ((size_t)((rgA + 0) * (KBS) + (T)) * 2) * 512 + lb;   \
        const _Float16* b1_ = ws + (ROFF) + ((size_t)((rgA + 1) * (KBS) + (T)) * 2) * 512 + lb;   \
        H0 = *(const half8*)b0_;  L0 = *(const half8*)(b0_ + 512);                                \
        H1 = *(const half8*)b1_;  L1 = *(const half8*)(b1_ + 512);                                \
    }

// MFMA block: reads W frags from smem[BB..], A from named regs.
#define MBLK(BB, NSETS, AH0, AL0, AH1, AL1)                                                       \
    {                                                                                             \
        __builtin_amdgcn_s_setprio(1);                                                            \
        _Pragma("unroll")                                                                         \
        for (int s = 0; s < (NSETS); ++s) {                                                       \
            _Pragma("unroll")                                                                     \
            for (int nt = 0; nt < 4; ++nt) {                                                      \
                half8 bh = *(const half8*)&smem[(BB) + (s * 4 + nt) * 512 + lb];                  \
                half8 bl = *(const half8*)&smem[(BB) + 8192 + (s * 4 + nt) * 512 + lb];           \
                acc[s][0][nt] = __builtin_amdgcn_mfma_f32_16x16x32_f16(AH0, bh, acc[s][0][nt], 0, 0, 0); \
                acc[s][0][nt] = __builtin_amdgcn_mfma_f32_16x16x32_f16(AL0, bh, acc[s][0][nt], 0, 0, 0); \
                acc[s][0][nt] = __builtin_amdgcn_mfma_f32_16x16x32_f16(AH0, bl, acc[s][0][nt], 0, 0, 0); \
                acc[s][1][nt] = __builtin_amdgcn_mfma_f32_16x16x32_f16(AH1, bh, acc[s][1][nt], 0, 0, 0); \
                acc[s][1][nt] = __builtin_amdgcn_mfma_f32_16x16x32_f16(AL1, bh, acc[s][1][nt], 0, 0, 0); \
                acc[s][1][nt] = __builtin_amdgcn_mfma_f32_16x16x32_f16(AH1, bl, acc[s][1][nt], 0, 0, 0); \
            }                                                                                     \
        }                                                                                         \
        __builtin_amdgcn_s_setprio(0);                                                            \
    }

// Counted-vmcnt barrier (m201 idiom): the 4 A loads issued after the W DMAs may
// remain in flight; all W DMAs must have landed. lgkmcnt(0) drains this wave's
// ds_reads (cross-wave WAR safety for the buffer the next DMA overwrites).
#define BARR()                                                                                    \
    {                                                                                             \
        __builtin_amdgcn_sched_barrier(0);                                                        \
        asm volatile("s_waitcnt vmcnt(4) lgkmcnt(0)" ::: "memory");                               \
        __builtin_amdgcn_s_barrier();                                                             \
        __builtin_amdgcn_sched_barrier(0);                                                        \
    }
#define FENCE() __builtin_amdgcn_sched_barrier(0)

    half8 ah0A, al0A, ah1A, al1A, ah0B, al0B, ah1B, al1B;

    // prologue: chunk 0 -> buf0 / A-regs
    dmaW1(0, 0);
    FENCE();
    LDA(XF_OFF, 32, 0, ah0A, al0A, ah1A, al1A);
    BARR();

    // ---- Phase 1: X vs {Win, gates}; chunks 0..31, unroll-by-2 for buffer parity
    #pragma unroll 1
    for (int t = 0; t < NCH1 - 2; t += 2) {
        dmaW1(t + 1, 1); FENCE(); LDA(XF_OFF, 32, t + 1, ah0B, al0B, ah1B, al1B);
        MBLK(0, 4, ah0A, al0A, ah1A, al1A)
        BARR();
        dmaW1(t + 2, 0); FENCE(); LDA(XF_OFF, 32, t + 2, ah0A, al0A, ah1A, al1A);
        MBLK(16384, 4, ah0B, al0B, ah1B, al1B)
        BARR();
    }
    // t=30: prefetch 31 (ph1); t=31: prefetch ph2 chunk 0
    dmaW1(31, 1); FENCE(); LDA(XF_OFF, 32, 31, ah0B, al0B, ah1B, al1B);
    MBLK(0, 4, ah0A, al0A, ah1A, al1A)
    BARR();
    dmaW2(0, 0); FENCE(); LDA(PF_OFF, 64, 0, ah0A, al0A, ah1A, al1A);
    MBLK(16384, 4, ah0B, al0B, ah1B, al1B)
    BARR();

    // ---- Phase 2: prev vs Wres; chunks 0..63 (chunk t lives in buf[t&1])
    #pragma unroll 1
    for (int t = 0; t < NCH2 - 2; t += 2) {
        dmaW2(t + 1, 1); FENCE(); LDA(PF_OFF, 64, t + 1, ah0B, al0B, ah1B, al1B);
        MBLK(0, 1, ah0A, al0A, ah1A, al1A)
        BARR();
        dmaW2(t + 2, 0); FENCE(); LDA(PF_OFF, 64, t + 2, ah0A, al0A, ah1A, al1A);
        MBLK(16384, 1, ah0B, al0B, ah1B, al1B)
        BARR();
    }
    // t=62: prefetch 63; t=63: no prefetch, no trailing barrier
    dmaW2(63, 1); FENCE(); LDA(PF_OFF, 64, 63, ah0B, al0B, ah1B, al1B);
    MBLK(0, 1, ah0A, al0A, ah1A, al1A)
    BARR();
    MBLK(16384, 1, ah0B, al0B, ah1B, al1B)

#undef MBLK
#undef LDA
#undef BARR
#undef FENCE

    // ---- epilogue: C/D layout col=lane&15, row=quad*4+reg (m89-verified) ----
    const int fr = lane & 15;
    const int qd = lane >> 4;
    #pragma unroll
    for (int mt = 0; mt < 2; ++mt)
        #pragma unroll
        for (int nt = 0; nt < 4; ++nt)
            #pragma unroll
            for (int r = 0; r < 4; ++r) {
                int row = m0 + wv * 32 + mt * 16 + qd * 4 + r;   // batch index
                int col = n0 + nt * 16 + fr;                      // reservoir index
                float pre = acc[0][mt][nt][r];
                float ig  = sigmoidf_(acc[1][mt][nt][r]);
                float fg  = sigmoidf_(acc[2][mt][nt][r]);
                float og  = sigmoidf_(acc[3][mt][nt][r]);
                float pv  = P[(size_t)row * MAXD + col];          // exact fp32 prev
                float st  = 0.9f * (fg * pv) + 0.1f * tanhf(ig * pre);
                st *= og;
                if (st > 0.5f) st -= 0.5f;
                out[(size_t)row * MAXD + col] = st;
            }
}

// =================== fallback path (no/short workspace) =====================
// Round-2 kernel verbatim (passed at 351 us standalone): in-kernel hi/lo split,
// fragment-major swizzled LDS, reg prefetch across lgkm-only barriers.
__device__ __forceinline__ void wg_barrier_ref() {
    __builtin_amdgcn_sched_barrier(0);
    asm volatile("s_waitcnt lgkmcnt(0)" ::: "memory");
    __builtin_amdgcn_s_barrier();
    __builtin_amdgcn_sched_barrier(0);
}

__global__ __launch_bounds__(256, 2)
void reservoir_ref(const float* __restrict__ X, const float* __restrict__ P,
                   const float* __restrict__ Win, const float* __restrict__ Wres,
                   const float* __restrict__ Wg, float* __restrict__ out)
{
    __shared__ _Float16 sA[2][8][512];
    __shared__ _Float16 sW[2][4][4][512];
    const int tid  = threadIdx.x;
    const int lane = tid & 63;
    const int wv   = tid >> 6;
    const int m0   = blockIdx.y * BM;
    const int n0   = blockIdx.x * BN;
    f32x4 acc[4][2][4];
    #pragma unroll
    for (int s = 0; s < 4; ++s)
        #pragma unroll
        for (int mt = 0; mt < 2; ++mt)
            #pragma unroll
            for (int nt = 0; nt < 4; ++nt) acc[s][mt][nt] = (f32x4){0.f, 0.f, 0.f, 0.f};
    const int crow = tid >> 3;
    const int c4   = (tid & 7) * 4;
    const int q    = c4 >> 3;
    const int fbase = q * 128 + (c4 & 4);
    const int raddr = ((((lane & 15) ^ (lane >> 4)) << 3) + ((lane >> 4) << 7));
    f32x4 pa[4];
    f32x4 pw[8];
    auto issue_loads = [&](int t) {
        if (t < NCH1) {
            const int kc = t * BK + c4;
            const float* a = X + (size_t)m0 * D_ + kc;
            #pragma unroll
            for (int i = 0; i < 4; ++i) pa[i] = *(const f32x4*)(a + (size_t)(crow + 32 * i) * D_);
            const float* w = Win + (size_t)n0 * D_ + kc;
            #pragma unroll
            for (int i = 0; i < 2; ++i) pw[i] = *(const f32x4*)(w + (size_t)(crow + 32 * i) * D_);
            const float* g = Wg + (size_t)n0 * D_ + kc;
            #pragma unroll
            for (int gg = 0; gg < 3; ++gg)
                #pragma unroll
                for (int i = 0; i < 2; ++i)
                    pw[2 + gg * 2 + i] = *(const f32x4*)(g + (size_t)(gg * R_ + crow + 32 * i) * D_);
        } else {
            const int kc = t * BK - D_ + c4;
            const float* a = P + (size_t)m0 * MAXD + kc;
            #pragma unroll
            for (int i = 0; i < 4; ++i) pa[i] = *(const f32x4*)(a + (size_t)(crow + 32 * i) * MAXD);
            const float* w = Wres + (size_t)n0 * R_ + kc;
            #pragma unroll
            for (int i = 0; i < 2; ++i) pw[i] = *(const f32x4*)(w + (size_t)(crow + 32 * i) * R_);
        }
    };
    auto stage_A = [&]() {
        #pragma unroll
        for (int i = 0; i < 4; ++i) {
            const int r = crow + 32 * i;
            const int idx = (((r & 15) ^ q) << 3) + fbase;
            half4 h, l;
            #pragma unroll
            for (int j = 0; j < 4; ++j) {
                float v = pa[i][j];
                h[j] = (_Float16)v;
                l[j] = (_Float16)(v - (float)h[j]);
            }
            *(half4*)(&sA[0][r >> 4][idx]) = h;
            *(half4*)(&sA[1][r >> 4][idx]) = l;
        }
    };
    auto stage_W = [&](int nw) {
        #pragma unroll
        for (int i = 0; i < 8; ++i) if (i < nw) {
            const int s   = (i < 2) ? 0 : 1 + ((i - 2) >> 1);
            const int sub = (i < 2) ? i : ((i - 2) & 1);
            const int r   = crow + 32 * sub;
            const int idx = (((r & 15) ^ q) << 3) + fbase;
            half4 h, l;
            #pragma unroll
            for (int j = 0; j < 4; ++j) {
                float v = pw[i][j];
                h[j] = (_Float16)v;
                l[j] = (_Float16)(v - (float)h[j]);
            }
            *(half4*)(&sW[0][s][r >> 4][idx]) = h;
            *(half4*)(&sW[1][s][r >> 4][idx]) = l;
        }
    };
#define RMFMA(NSETS)                                                                              \
    {                                                                                             \
        half8 ah0 = *(const half8*)(&sA[0][wv * 2 + 0][raddr]);                                   \
        half8 al0 = *(const half8*)(&sA[1][wv * 2 + 0][raddr]);                                   \
        half8 ah1 = *(const half8*)(&sA[0][wv * 2 + 1][raddr]);                                   \
        half8 al1 = *(const half8*)(&sA[1][wv * 2 + 1][raddr]);                                   \
        _Pragma("unroll")                                                                         \
        for (int s = 0; s < NSETS; ++s) {                                                         \
            _Pragma("unroll")                                                                     \
            for (int nt = 0; nt < 4; ++nt) {                                                      \
                half8 bh = *(const half8*)(&sW[0][s][nt][raddr]);                                 \
                half8 bl = *(const half8*)(&sW[1][s][nt][raddr]);                                 \
                acc[s][0][nt] = __builtin_amdgcn_mfma_f32_16x16x32_f16(ah0, bh, acc[s][0][nt], 0, 0, 0); \
                acc[s][0][nt] = __builtin_amdgcn_mfma_f32_16x16x32_f16(al0, bh, acc[s][0][nt], 0, 0, 0); \
                acc[s][0][nt] = __builtin_amdgcn_mfma_f32_16x16x32_f16(ah0, bl, acc[s][0][nt], 0, 0, 0); \
                acc[s][1][nt] = __builtin_amdgcn_mfma_f32_16x16x32_f16(ah1, bh, acc[s][1][nt], 0, 0, 0); \
                acc[s][1][nt] = __builtin_amdgcn_mfma_f32_16x16x32_f16(al1, bh, acc[s][1][nt], 0, 0, 0); \
                acc[s][1][nt] = __builtin_amdgcn_mfma_f32_16x16x32_f16(ah1, bl, acc[s][1][nt], 0, 0, 0); \
            }                                                                                     \
        }                                                                                         \
    }
    issue_loads(0);
    #pragma unroll 1
    for (int t = 0; t < NCH1; ++t) {
        stage_A(); stage_W(8);
        issue_loads(t + 1);
        wg_barrier_ref();
        RMFMA(4)
        wg_barrier_ref();
    }
    #pragma unroll 1
    for (int t = NCH1; t < NCH1 + NCH2; ++t) {
        stage_A(); stage_W(2);
        if (t + 1 < NCH1 + NCH2) issue_loads(t + 1);
        wg_barrier_ref();
        RMFMA(1)
        wg_barrier_ref();
    }
#undef RMFMA
    const int fr = lane & 15;
    const int qd = lane >> 4;
    #pragma unroll
    for (int mt = 0; mt < 2; ++mt)
        #pragma unroll
        for (int nt = 0; nt < 4; ++nt)
            #pragma unroll
            for (int r = 0; r < 4; ++r) {
                int row = m0 + wv * 32 + mt * 16 + qd * 4 + r;
                int col = n0 + nt * 16 + fr;
                float pre = acc[0][mt][nt][r];
                float ig  = sigmoidf_(acc[1][mt][nt][r]);
                float fg  = sigmoidf_(acc[2][mt][nt][r]);
                float og  = sigmoidf_(acc[3][mt][nt][r]);
                float pv  = P[(size_t)row * MAXD + col];
                float st  = 0.9f * (fg * pv) + 0.1f * tanhf(ig * pre);
                st *= og;
                if (st > 0.5f) st -= 0.5f;
                out[(size_t)row * MAXD + col] = st;
            }
}

__global__ void pad_zero(float* __restrict__ out) {
    int idx = blockIdx.x * 256 + threadIdx.x;
    int row = idx >> 7;
    int c   = (idx & 127) * 4;
    *(f32x4*)(&out[(size_t)row * MAXD + R_ + c]) = (f32x4){0.f, 0.f, 0.f, 0.f};
}

extern "C" void kernel_launch(void* const* d_in, const int* in_sizes, int n_in,
                              void* d_out, int out_size, void* d_ws, size_t ws_size,
                              hipStream_t stream) {
    const float* X    = (const float*)d_in[0];
    const float* P    = (const float*)d_in[1];
    const float* Win  = (const float*)d_in[2];
    const float* Wres = (const float*)d_in[3];
    const float* Wg   = (const float*)d_in[4];
    float* out        = (float*)d_out;

    dim3 grid(R_ / BN, B_ / BM);   // (32, 32) = 1024 blocks

    if (d_ws != nullptr && ws_size >= WS_BYTES) {
        _Float16* ws = (_Float16*)d_ws;
        prep<<<(NPACK_WTASKS + NPAD_WTASKS) / 4, 256, 0, stream>>>(X, P, Win, Wres, Wg, ws, out);
        reservoir_packed<<<grid, 256, 0, stream>>>((const _Float16*)ws, P, out);
    } else {
        pad_zero<<<2048, 256, 0, stream>>>(out);
        reservoir_ref<<<grid, 256, 0, stream>>>(X, P, Win, Wres, Wg, out);
    }
}